// Round 6
// baseline (86.813 us; speedup 1.0000x reference)
//
#include <hip/hip_runtime.h>
#include <math.h>

#define HDIM   512
#define NH     32
#define NP     16                 // mode pairs
#define LLEN   8192
#define BLOCK  256
#define LSPLIT 2
#define LPB    (LLEN / LSPLIT)    // 4096 l per block
#define LPT    16                 // consecutive l per thread

typedef float vf2 __attribute__((ext_vector_type(2)));

// guaranteed packed fp32 (gfx90a+/gfx950 VOP3P), 64-bit VGPR-pair operands
static __device__ inline vf2 pk_mul(vf2 a, vf2 b) {
    vf2 d; asm("v_pk_mul_f32 %0, %1, %2" : "=v"(d) : "v"(a), "v"(b)); return d;
}
static __device__ inline vf2 pk_add(vf2 a, vf2 b) {
    vf2 d; asm("v_pk_add_f32 %0, %1, %2" : "=v"(d) : "v"(a), "v"(b)); return d;
}
static __device__ inline vf2 pk_fma(vf2 a, vf2 b, vf2 c) {   // a*b + c
    vf2 d; asm("v_pk_fma_f32 %0, %1, %2, %3" : "=v"(d) : "v"(a), "v"(b), "v"(c)); return d;
}
static __device__ inline vf2 pk_fms(vf2 a, vf2 b, vf2 c) {   // a*b - c
    vf2 d; asm("v_pk_fma_f32 %0, %1, %2, %3 neg_lo:[0,0,1] neg_hi:[0,0,1]"
               : "=v"(d) : "v"(a), "v"(b), "v"(c)); return d;
}

// ---- d_ws layout (float4 units) ----
#define TABA_F4  (HDIM * NP * 16)            // 131072: [(h*NP+P)*16 + lo]
#define TABB_F4  (HDIM * 2 * NP * 16)        // 262144: [((h*2+ls)*NP+P)*16 + hi]
#define PAD_F4   64
#define TABB_OFF (TABA_F4 + PAD_F4)
#define CST_OFF  (TABB_OFF + TABB_F4 + PAD_F4)  // [(h*NP+P)*3 + k]

// ---------------- prep kernel: all fp64 math, once per (h,n) ----------------
__global__ __launch_bounds__(64) void s4d_prep(
    const float* __restrict__ C, const float* __restrict__ log_dt,
    const float* __restrict__ log_A_real, const float* __restrict__ A_imag,
    float* __restrict__ ws)
{
    const int idx = blockIdx.x * 64 + threadIdx.x;   // 0..16383
    const int h = idx >> 5, n = idx & 31;
    const int P = n >> 1,  o = n & 1;

    const double dt  = exp((double)log_dt[h]);
    const double Are = -exp((double)log_A_real[h * NH + n]);
    const double Aim = (double)A_imag[h * NH + n];
    const double dre = Are * dt, dim = Aim * dt;

    double s1, c1; sincos(dim, &s1, &c1);
    const double em  = exp(dre);
    const double w1r = em * c1, w1i = em * s1;

    // 2*C_scaled = 2*Cc*(exp(dtA)-1)/A
    const double nre = w1r - 1.0, nim = w1i;
    const double den = Are * Are + Aim * Aim;
    const double fre = (nre * Are + nim * Aim) / den;
    const double fim = (nim * Are - nre * Aim) / den;
    const double Cre = (double)C[(h * NH + n) * 2 + 0];
    const double Cim = (double)C[(h * NH + n) * 2 + 1];
    const double csr = 2.0 * (Cre * fre - Cim * fim);
    const double csi = 2.0 * (Cre * fim + Cim * fre);

    // per-pair constants: {wr,wi}, {p,q}, {p2,q2}; lane slot o of each pair
    {
        const double p  = 2.0 * w1r, q = em * em;
        const double p2 = 2.0 * (w1r * w1r - w1i * w1i), q2 = q * q;
        float* cc = ws + (size_t)CST_OFF * 4 + (size_t)(h * NP + P) * 12;
        cc[0 + o]  = (float)w1r;  cc[2 + o]  = (float)w1i;
        cc[4 + o]  = (float)p;    cc[6 + o]  = (float)q;
        cc[8 + o]  = (float)p2;   cc[10 + o] = (float)q2;
    }

    // tabA: Cs * exp(dtA*16*lo), lo=0..15 (fp64 chain)
    {
        double ss, cs; sincos(dim * 16.0, &ss, &cs);
        const double ms = exp(dre * 16.0);
        const double str = ms * cs, sti = ms * ss;
        double gr = csr, gi = csi;
        float* ta = ws + (size_t)(h * NP + P) * 16 * 4;
        for (int lo = 0; lo < 16; ++lo) {
            ta[lo * 4 + o]     = (float)gr;
            ta[lo * 4 + 2 + o] = (float)gi;
            const double t = gr * str - gi * sti;
            gi = gr * sti + gi * str; gr = t;
        }
    }

    // tabB: exp(dtA*(LPB*ls + 256*hi)) — one fp64 chain of 32 covers both ls
    {
        double ss, cs; sincos(dim * 256.0, &ss, &cs);
        const double ms = exp(dre * 256.0);
        const double str = ms * cs, sti = ms * ss;
        double er = 1.0, ei = 0.0;
        for (int ls = 0; ls < 2; ++ls) {
            float* tb = ws + (size_t)TABB_OFF * 4
                           + (size_t)(((h * 2 + ls) * NP + P) * 16) * 4;
            for (int hi = 0; hi < 16; ++hi) {
                tb[hi * 4 + o]     = (float)er;
                tb[hi * 4 + 2 + o] = (float)ei;
                const double t = er * str - ei * sti;
                ei = er * sti + ei * str; er = t;
            }
        }
    }
}

// ---------------- main kernel: pure fp32 packed streaming ----------------
__global__ __launch_bounds__(BLOCK) void s4d_main(
    const float4* __restrict__ ws4, float* __restrict__ out)
{
    const int h  = blockIdx.y, ls = blockIdx.x, tid = threadIdx.x;
    const int lo = tid & 15,  hi = tid >> 4;    // 16*tid = 256*hi + 16*lo

    const float4* pa = ws4 + (size_t)(h * NP) * 16 + lo;
    const float4* pb = ws4 + TABB_OFF + (size_t)((h * 2 + ls) * NP) * 16 + hi;
    const float4* pc = ws4 + CST_OFF + (size_t)(h * NP) * 3;

    vf2 acc[LPT];
#pragma unroll
    for (int l = 0; l < LPT; ++l) acc[l] = (vf2)(0.f);

    float4 a4 = pa[0], b4 = pb[0];

#pragma unroll 1
    for (int P = 0; P < NP; ++P) {
        const float4 na = pa[(P + 1) * 16];   // prefetch (pads absorb last)
        const float4 nb = pb[(P + 1) * 16];
        const float4 c0 = pc[P * 3 + 0];
        const float4 c1 = pc[P * 3 + 1];
        const float4 c2 = pc[P * 3 + 2];

        const vf2 Ax = {a4.x, a4.y}, Ay = {a4.z, a4.w};
        const vf2 Bx = {b4.x, b4.y}, By = {b4.z, b4.w};
        const vf2 wr = {c0.x, c0.y}, wi = {c0.z, c0.w};
        const vf2 p  = {c1.x, c1.y}, q  = {c1.z, c1.w};
        const vf2 p2 = {c2.x, c2.y}, q2 = {c2.z, c2.w};

        // T = A'.B (Cs folded into A'); seeds y0..y3
        const vf2 Tr = pk_fms(Ax, Bx, pk_mul(Ay, By));
        const vf2 Ti = pk_fma(Ax, By, pk_mul(Ay, Bx));
        const vf2 y0 = Tr;
        const vf2 y1 = pk_fms(Tr, wr, pk_mul(Ti, wi));
        const vf2 y2 = pk_fms(p, y1, pk_mul(q, y0));
        const vf2 y3 = pk_fms(p, y2, pk_mul(q, y1));
        acc[0] = pk_add(acc[0], y0);
        acc[1] = pk_add(acc[1], y1);
        acc[2] = pk_add(acc[2], y2);
        acc[3] = pk_add(acc[3], y3);

        vf2 e0 = y0, e1 = y2, o0 = y1, o1 = y3;
#pragma unroll
        for (int m = 0; m < 6; ++m) {
            const vf2 e2 = pk_fms(p2, e1, pk_mul(q2, e0));
            const vf2 o2 = pk_fms(p2, o1, pk_mul(q2, o0));
            acc[4 + 2 * m] = pk_add(acc[4 + 2 * m], e2);
            acc[5 + 2 * m] = pk_add(acc[5 + 2 * m], o2);
            e0 = e1; e1 = e2;
            o0 = o1; o1 = o2;
        }
        a4 = na; b4 = nb;
    }

    // epilogue: horizontal add over pair lanes, 4x float4 stores
    float* orow = out + (size_t)h * LLEN + ls * LPB + LPT * tid;
#pragma unroll
    for (int j = 0; j < 4; ++j) {
        *(float4*)(orow + 4 * j) = make_float4(
            acc[4*j+0].x + acc[4*j+0].y,
            acc[4*j+1].x + acc[4*j+1].y,
            acc[4*j+2].x + acc[4*j+2].y,
            acc[4*j+3].x + acc[4*j+3].y);
    }
}

extern "C" void kernel_launch(void* const* d_in, const int* in_sizes, int n_in,
                              void* d_out, int out_size, void* d_ws, size_t ws_size,
                              hipStream_t stream) {
    const float* C          = (const float*)d_in[0];
    const float* log_dt     = (const float*)d_in[1];
    const float* log_A_real = (const float*)d_in[2];
    const float* A_imag     = (const float*)d_in[3];
    float* out = (float*)d_out;
    float* ws  = (float*)d_ws;

    s4d_prep<<<HDIM * NH / 64, 64, 0, stream>>>(C, log_dt, log_A_real, A_imag, ws);
    dim3 grid(LSPLIT, HDIM);
    s4d_main<<<grid, BLOCK, 0, stream>>>((const float4*)ws, out);
}

// Round 7
// 80.342 us; speedup vs baseline: 1.0805x; 1.0805x over previous
//
#include <hip/hip_runtime.h>
#include <math.h>

#define HDIM   512
#define NH     32
#define NP     16                 // mode pairs
#define LLEN   8192
#define BLOCK  256
#define LSPLIT 2
#define LPB    (LLEN / LSPLIT)    // 4096 l per block
#define LPT    16                 // consecutive l per thread

typedef float vf2 __attribute__((ext_vector_type(2)));

// guaranteed packed fp32 (gfx90a+/gfx950 VOP3P), 64-bit VGPR-pair operands
static __device__ inline vf2 pk_mul(vf2 a, vf2 b) {
    vf2 d; asm("v_pk_mul_f32 %0, %1, %2" : "=v"(d) : "v"(a), "v"(b)); return d;
}
static __device__ inline vf2 pk_add(vf2 a, vf2 b) {
    vf2 d; asm("v_pk_add_f32 %0, %1, %2" : "=v"(d) : "v"(a), "v"(b)); return d;
}
static __device__ inline vf2 pk_fma(vf2 a, vf2 b, vf2 c) {   // a*b + c
    vf2 d; asm("v_pk_fma_f32 %0, %1, %2, %3" : "=v"(d) : "v"(a), "v"(b), "v"(c)); return d;
}
static __device__ inline vf2 pk_fms(vf2 a, vf2 b, vf2 c) {   // a*b - c
    vf2 d; asm("v_pk_fma_f32 %0, %1, %2, %3 neg_lo:[0,0,1] neg_hi:[0,0,1]"
               : "=v"(d) : "v"(a), "v"(b), "v"(c)); return d;
}

// Grid (LSPLIT, HDIM). Thread tid owns l in [ls*LPB + 16*tid, +16).
// y_l = Re(2Cs w^l) obeys y_{l+2} = p2*y_l - q2*y_{l-2}; even/odd chains
// decouple. Mode PAIRS processed with forced v_pk_* (2 modes/inst).
// tabA has 2*C_scaled folded in (fp64-built, in-block prologue).
__global__ __launch_bounds__(BLOCK) void s4d_kernel(
    const float* __restrict__ C,          // (H, NH, 2)
    const float* __restrict__ log_dt,     // (H,)
    const float* __restrict__ log_A_real, // (H, NH)
    const float* __restrict__ A_imag,     // (H, NH)
    float* __restrict__ out)              // (H, LLEN)
{
    __shared__ float4 tabA[NP + 1][16];   // {Axa,Axb,Aya,Ayb}: 2Cs*exp(dtA*16lo)
    __shared__ float4 tabB[NP + 1][16];   // {Bxa,Bxb,Bya,Byb}: exp(dtA*(LPB*ls+256hi))
    __shared__ float4 s_w [NP + 1];       // {wra,wrb,wia,wib}
    __shared__ float4 s_pq[NP + 1];       // {pa,pb,qa,qb}
    __shared__ float4 s_p2[NP + 1];       // {p2a,p2b,q2a,q2b}

    const int h   = blockIdx.y;
    const int ls  = blockIdx.x;
    const int tid = threadIdx.x;

    // ---------------- prep (fp64): packed tables + constants ----------------
    {
        const int n = tid & 31;
        const int g = tid >> 5;            // 0..3 -> tabA, 4..7 -> tabB
        const int P = n >> 1, o = n & 1;
        const double dt  = exp((double)log_dt[h]);
        const double Are = -exp((double)log_A_real[h * NH + n]);
        const double Aim = (double)A_imag[h * NH + n];
        const double dre = Are * dt, dim = Aim * dt;

        double s1, c1; sincos(dim, &s1, &c1);
        const double em  = exp(dre);
        const double w1r = em * c1, w1i = em * s1;

        float* tabAf = (float*)&tabA[0][0];
        float* tabBf = (float*)&tabB[0][0];

        if (g < 4) {
            // 2*C_scaled (fp64)
            const double nre = w1r - 1.0, nim = w1i;
            const double den = Are * Are + Aim * Aim;
            const double fre = (nre * Are + nim * Aim) / den;
            const double fim = (nim * Are - nre * Aim) / den;
            const double Cre = (double)C[(h * NH + n) * 2 + 0];
            const double Cim = (double)C[(h * NH + n) * 2 + 1];
            const double csr = 2.0 * (Cre * fre - Cim * fim);
            const double csi = 2.0 * (Cre * fim + Cim * fre);

            const int    i0   = g * 4;
            const double base = 16.0 * (double)i0;
            double s0, c0; sincos(dim * base, &s0, &c0);
            const double m0 = exp(dre * base);
            const double er = m0 * c0, ei = m0 * s0;
            double gr = csr * er - csi * ei;
            double gi = csr * ei + csi * er;
            double ss, cs; sincos(dim * 16.0, &ss, &cs);
            const double ms  = exp(dre * 16.0);
            const double str = ms * cs, sti = ms * ss;
            for (int k = 0; k < 4; ++k) {
                const int idx = (P * 16 + i0 + k) * 4;
                tabAf[idx + o]     = (float)gr;
                tabAf[idx + 2 + o] = (float)gi;
                const double t = gr * str - gi * sti;
                gi = gr * sti + gi * str;
                gr = t;
            }
        } else {
            const int    i0   = (g - 4) * 4;
            const double base = (double)(LPB * ls) + 256.0 * (double)i0;
            double s0, c0; sincos(dim * base, &s0, &c0);
            const double m0 = exp(dre * base);
            double er = m0 * c0, ei = m0 * s0;
            double ss, cs; sincos(dim * 256.0, &ss, &cs);
            const double ms  = exp(dre * 256.0);
            const double str = ms * cs, sti = ms * ss;
            for (int k = 0; k < 4; ++k) {
                const int idx = (P * 16 + i0 + k) * 4;
                tabBf[idx + o]     = (float)er;
                tabBf[idx + 2 + o] = (float)ei;
                const double t = er * str - ei * sti;
                ei = er * sti + ei * str;
                er = t;
            }
        }

        if (g == 0) {
            float* wf  = (float*)&s_w[0];
            float* pqf = (float*)&s_pq[0];
            float* p2f = (float*)&s_p2[0];
            const double p  = 2.0 * w1r;
            const double q  = em * em;
            const double p2 = 2.0 * (w1r * w1r - w1i * w1i);
            const double q2 = q * q;
            wf [P * 4 + o]     = (float)w1r;
            wf [P * 4 + 2 + o] = (float)w1i;
            pqf[P * 4 + o]     = (float)p;
            pqf[P * 4 + 2 + o] = (float)q;
            p2f[P * 4 + o]     = (float)p2;
            p2f[P * 4 + 2 + o] = (float)q2;
        }
    }
    __syncthreads();

    const int lo = tid & 15, hi = tid >> 4;   // 16*tid = 256*hi + 16*lo

    vf2 acc[LPT];
#pragma unroll
    for (int l = 0; l < LPT; ++l) acc[l] = (vf2)(0.f);

    float4 a4 = tabA[0][lo], b4 = tabB[0][hi];
    float4 c0 = s_w[0], c1 = s_pq[0], c2 = s_p2[0];

#pragma unroll 2
    for (int P = 0; P < NP; ++P) {
        // prefetch next pair's LDS data (row NP is padding)
        const float4 na = tabA[P + 1][lo], nb = tabB[P + 1][hi];
        const float4 n0 = s_w[P + 1], n1 = s_pq[P + 1], n2 = s_p2[P + 1];

        const vf2 Ax = {a4.x, a4.y}, Ay = {a4.z, a4.w};
        const vf2 Bx = {b4.x, b4.y}, By = {b4.z, b4.w};
        const vf2 wr = {c0.x, c0.y}, wi = {c0.z, c0.w};
        const vf2 p  = {c1.x, c1.y}, q  = {c1.z, c1.w};
        const vf2 p2 = {c2.x, c2.y}, q2 = {c2.z, c2.w};

        // T = A'.B (Cs folded into A'); seeds y0..y3
        const vf2 Tr = pk_fms(Ax, Bx, pk_mul(Ay, By));
        const vf2 Ti = pk_fma(Ax, By, pk_mul(Ay, Bx));
        const vf2 y0 = Tr;
        const vf2 y1 = pk_fms(Tr, wr, pk_mul(Ti, wi));
        const vf2 y2 = pk_fms(p, y1, pk_mul(q, y0));
        const vf2 y3 = pk_fms(p, y2, pk_mul(q, y1));
        acc[0] = pk_add(acc[0], y0);
        acc[1] = pk_add(acc[1], y1);
        acc[2] = pk_add(acc[2], y2);
        acc[3] = pk_add(acc[3], y3);

        vf2 e0 = y0, e1 = y2, o0 = y1, o1 = y3;
#pragma unroll
        for (int m = 0; m < 6; ++m) {
            const vf2 e2 = pk_fms(p2, e1, pk_mul(q2, e0));
            const vf2 o2 = pk_fms(p2, o1, pk_mul(q2, o0));
            acc[4 + 2 * m] = pk_add(acc[4 + 2 * m], e2);
            acc[5 + 2 * m] = pk_add(acc[5 + 2 * m], o2);
            e0 = e1; e1 = e2;
            o0 = o1; o1 = o2;
        }
        a4 = na; b4 = nb; c0 = n0; c1 = n1; c2 = n2;
    }

    // epilogue: horizontal add over pair lanes, 4x float4 stores
    float* orow = out + (size_t)h * LLEN + ls * LPB + LPT * tid;
#pragma unroll
    for (int j = 0; j < 4; ++j) {
        *(float4*)(orow + 4 * j) = make_float4(
            acc[4*j+0].x + acc[4*j+0].y,
            acc[4*j+1].x + acc[4*j+1].y,
            acc[4*j+2].x + acc[4*j+2].y,
            acc[4*j+3].x + acc[4*j+3].y);
    }
}

extern "C" void kernel_launch(void* const* d_in, const int* in_sizes, int n_in,
                              void* d_out, int out_size, void* d_ws, size_t ws_size,
                              hipStream_t stream) {
    const float* C          = (const float*)d_in[0];
    const float* log_dt     = (const float*)d_in[1];
    const float* log_A_real = (const float*)d_in[2];
    const float* A_imag     = (const float*)d_in[3];
    float* out = (float*)d_out;

    dim3 grid(LSPLIT, HDIM);
    s4d_kernel<<<grid, BLOCK, 0, stream>>>(C, log_dt, log_A_real, A_imag, out);
}